// Round 8
// baseline (269.148 us; speedup 1.0000x reference)
//
#include <hip/hip_runtime.h>
#include <math.h>

constexpr int NB = 2;
constexpr int NS = 2048;
constexpr int ND = 1024;
constexpr int NH = 16;
constexpr int NDK = 64;

typedef __attribute__((ext_vector_type(8))) short short8;
typedef __attribute__((ext_vector_type(4))) float floatx4;

__device__ inline unsigned short f2bf(float x) {
    unsigned u = __builtin_bit_cast(unsigned, x);
    u += 0x7fffu + ((u >> 16) & 1u);          // RNE
    return (unsigned short)(u >> 16);
}

__device__ inline uint4 pack8(float4 a, float4 b) {
    unsigned short t[8] = {f2bf(a.x), f2bf(a.y), f2bf(a.z), f2bf(a.w),
                           f2bf(b.x), f2bf(b.y), f2bf(b.z), f2bf(b.w)};
    return *(uint4*)t;
}

#define GLOAD_LDS16(g, l) __builtin_amdgcn_global_load_lds( \
    (const __attribute__((address_space(1))) void*)(g),     \
    (__attribute__((address_space(3))) void*)(l), 16, 0, 0)

// scale folded into Q projection: exp(s/8) == exp2(s * 0.125 * log2(e))
#define QSCALE 0.18033688f

// ---------------------------------------------------------------------------
// Fused QKV projection, fp32 inputs (convert folded into staging).
// 128x128 tile, BK=32, 4 waves 2x2 (64x64 each). 768 blocks:
//   seg 0: qbuf = (Xq @ Wq^T + bq) * QSCALE      (bf16)
//   seg 1: kbuf =  Xk @ Wk^T + bk                (bf16)
//   seg 2: vt[(b*ND+d)][s] = Wv @ Xv^T + bv      (V^T direct, bf16)
// Staging: per thread 2 A-chunks + 2 B-chunks of 8 fp32 -> pack -> b128 write,
// register-prefetched one K-iter ahead so global loads overlap MFMA.
// ---------------------------------------------------------------------------
__global__ __launch_bounds__(256) void gemm_qkv(
    const float* __restrict__ Xq, const float* __restrict__ Xk,
    const float* __restrict__ Xv,
    const float* __restrict__ Wq, const float* __restrict__ Wk,
    const float* __restrict__ Wv,
    const float* __restrict__ bq, const float* __restrict__ bk,
    const float* __restrict__ bv,
    unsigned short* __restrict__ Cq, unsigned short* __restrict__ Ck,
    unsigned short* __restrict__ Cv)
{
    __shared__ unsigned short As[128 * 32];
    __shared__ unsigned short Bs[128 * 32];
    const int tid = threadIdx.x, w = tid >> 6, lane = tid & 63;
    const int lo = lane & 15, quad = lane >> 4;
    const int bid = blockIdx.x;
    const int seg = bid >> 8;          // 0,1,2 (256 blocks each)
    const int wi  = bid & 255;
    const int K = ND;

    int bm, bn;
    const float *A, *Bw, *bias;
    if (seg == 2)      { bn = wi & 31; bm = wi >> 5; A = Wv; Bw = Xv; bias = bv; }
    else if (seg == 1) { bn = wi & 7;  bm = wi >> 3; A = Xk; Bw = Wk; bias = bk; }
    else               { bn = wi & 7;  bm = wi >> 3; A = Xq; Bw = Wq; bias = bq; }

    const int wm = (w >> 1) * 64, wn = (w & 1) * 64;

    // chunk c = tid covers row tid>>2 (0..63), c = tid+256 covers row+64;
    // LDS position p=tid&3 holds global chunk p ^ (row&3).
    const int srow = tid >> 2;
    const int sch = (tid & 3) ^ (srow & 3);
    const float* Ag0 = A + (size_t)(bm * 128 + srow) * K + sch * 8;
    const float* Ag1 = Ag0 + (size_t)64 * K;
    const float* Bg0 = Bw + (size_t)(bn * 128 + srow) * K + sch * 8;
    const float* Bg1 = Bg0 + (size_t)64 * K;
    unsigned short* AsD0 = As + tid * 8;
    unsigned short* AsD1 = As + (tid + 256) * 8;
    unsigned short* BsD0 = Bs + tid * 8;
    unsigned short* BsD1 = Bs + (tid + 256) * 8;

    floatx4 acc[4][4];
    #pragma unroll
    for (int i = 0; i < 4; ++i)
        #pragma unroll
        for (int j = 0; j < 4; ++j) acc[i][j] = (floatx4){0.f, 0.f, 0.f, 0.f};

    const int rpos = (quad ^ (lo & 3)) * 8;

    // prefetch first tile into registers
    float4 ra[4], rb[4];
    ra[0] = *(const float4*)(Ag0);     ra[1] = *(const float4*)(Ag0 + 4);
    ra[2] = *(const float4*)(Ag1);     ra[3] = *(const float4*)(Ag1 + 4);
    rb[0] = *(const float4*)(Bg0);     rb[1] = *(const float4*)(Bg0 + 4);
    rb[2] = *(const float4*)(Bg1);     rb[3] = *(const float4*)(Bg1 + 4);

    for (int k0 = 0; k0 < K; k0 += 32) {
        __syncthreads();
        *(uint4*)AsD0 = pack8(ra[0], ra[1]);
        *(uint4*)AsD1 = pack8(ra[2], ra[3]);
        *(uint4*)BsD0 = pack8(rb[0], rb[1]);
        *(uint4*)BsD1 = pack8(rb[2], rb[3]);
        __syncthreads();

        const int kn = k0 + 32;
        if (kn < K) {
            ra[0] = *(const float4*)(Ag0 + kn); ra[1] = *(const float4*)(Ag0 + kn + 4);
            ra[2] = *(const float4*)(Ag1 + kn); ra[3] = *(const float4*)(Ag1 + kn + 4);
            rb[0] = *(const float4*)(Bg0 + kn); rb[1] = *(const float4*)(Bg0 + kn + 4);
            rb[2] = *(const float4*)(Bg1 + kn); rb[3] = *(const float4*)(Bg1 + kn + 4);
        }

        short8 af[4], bf[4];
        #pragma unroll
        for (int i = 0; i < 4; ++i)
            af[i] = *(const short8*)(As + (wm + i * 16 + lo) * 32 + rpos);
        #pragma unroll
        for (int j = 0; j < 4; ++j)
            bf[j] = *(const short8*)(Bs + (wn + j * 16 + lo) * 32 + rpos);

        #pragma unroll
        for (int i = 0; i < 4; ++i)
            #pragma unroll
            for (int j = 0; j < 4; ++j)
                acc[i][j] = __builtin_amdgcn_mfma_f32_16x16x32_bf16(af[i], bf[j], acc[i][j], 0, 0, 0);
    }

    if (seg < 2) {
        unsigned short* C = seg ? Ck : Cq;
        const float scale = seg ? 1.f : QSCALE;
        #pragma unroll
        for (int j = 0; j < 4; ++j) {
            const int col = bn * 128 + wn + j * 16 + lo;
            const float bb = bias[col];
            #pragma unroll
            for (int i = 0; i < 4; ++i)
                #pragma unroll
                for (int r = 0; r < 4; ++r) {
                    const int row = bm * 128 + wm + i * 16 + quad * 4 + r;
                    C[(size_t)row * ND + col] = f2bf((acc[i][j][r] + bb) * scale);
                }
        }
    } else {
        // rows = d (0..1023), cols = tokens; write vt[(b*ND + d)*NS + s]
        #pragma unroll
        for (int i = 0; i < 4; ++i)
            #pragma unroll
            for (int r = 0; r < 4; ++r) {
                const int row = bm * 128 + wm + i * 16 + quad * 4 + r;
                const float bb = bias[row];
                #pragma unroll
                for (int j = 0; j < 4; ++j) {
                    const int col = bn * 128 + wn + j * 16 + lo;
                    const int b = col >> 11, s = col & (NS - 1);
                    Cv[(size_t)(b * ND + row) * NS + s] = f2bf(acc[i][j][r] + bb);
                }
            }
    }
}

// ---------------------------------------------------------------------------
// MFMA flash attention, K-split x2 into separate partial buffers (no atomics,
// no memset). No-max softmax; operand-swapped QK^T; LDS-staged K/V tiles.
// ---------------------------------------------------------------------------
constexpr int PRS = 72;

__global__ __launch_bounds__(256, 4) void attn_mfma(
    const unsigned short* __restrict__ qb,
    const unsigned short* __restrict__ kb,
    const unsigned short* __restrict__ vt,
    float* __restrict__ cacc0, float* __restrict__ cacc1,
    float* __restrict__ lbuf)
{
    __shared__ unsigned short Ks[64 * 64];
    __shared__ unsigned short Vs[64 * 64];
    __shared__ unsigned short Pt[4][32 * PRS];

    const int tid = threadIdx.x, w = tid >> 6, lane = tid & 63;
    const int lo = lane & 15, quad = lane >> 4;
    const int qgrp = blockIdx.x;          // 0..15
    const int ksp  = blockIdx.y;          // 0..1
    const int bh   = blockIdx.z;          // 0..31
    const int b = bh >> 4, h = bh & 15;
    const int q0 = qgrp * 128 + w * 32;

    short8 qf[2][2];
    #pragma unroll
    for (int qt = 0; qt < 2; ++qt) {
        const unsigned short* qrow =
            qb + (size_t)(b * NS + q0 + qt * 16 + lo) * ND + h * NDK + quad * 8;
        qf[qt][0] = *(const short8*)(qrow);
        qf[qt][1] = *(const short8*)(qrow + 32);
    }

    // staging: 64-row x 128B tiles = 512 x 16B chunks, 2 per thread
    const int c0 = tid, c1 = tid + 256;
    const int r0 = c0 >> 3, g0 = (c0 & 7) ^ (r0 & 7);
    const int r1 = c1 >> 3, g1 = (c1 & 7) ^ (r1 & 7);
    const unsigned short* Ksrc0 = kb + (size_t)(b * NS + r0) * ND + h * NDK + g0 * 8;
    const unsigned short* Ksrc1 = kb + (size_t)(b * NS + r1) * ND + h * NDK + g1 * 8;
    const unsigned short* Vsrc0 = vt + (size_t)(bh * NDK + r0) * NS + g0 * 8;
    const unsigned short* Vsrc1 = vt + (size_t)(bh * NDK + r1) * NS + g1 * 8;
    unsigned short* Kd0 = Ks + c0 * 8;
    unsigned short* Kd1 = Ks + c1 * 8;
    unsigned short* Vd0 = Vs + c0 * 8;
    unsigned short* Vd1 = Vs + c1 * 8;

    floatx4 acc[2][4], lacc[2];
    #pragma unroll
    for (int qt = 0; qt < 2; ++qt) {
        lacc[qt] = (floatx4){0.f, 0.f, 0.f, 0.f};
        #pragma unroll
        for (int cb = 0; cb < 4; ++cb) acc[qt][cb] = (floatx4){0.f, 0.f, 0.f, 0.f};
    }

    const short8 ones = {0x3F80, 0x3F80, 0x3F80, 0x3F80,
                         0x3F80, 0x3F80, 0x3F80, 0x3F80};
    unsigned short* pw = &Pt[w][0];
    const int pos0 = (quad ^ (lo & 7)) * 8;
    const int pos1 = ((4 + quad) ^ (lo & 7)) * 8;

    for (int key0 = ksp * 1024; key0 < ksp * 1024 + 1024; key0 += 64) {
        GLOAD_LDS16(Ksrc0 + (size_t)key0 * ND, Kd0);
        GLOAD_LDS16(Ksrc1 + (size_t)key0 * ND, Kd1);
        GLOAD_LDS16(Vsrc0 + key0, Vd0);
        GLOAD_LDS16(Vsrc1 + key0, Vd1);
        __syncthreads();

        // S^T = K @ Q^T : lane holds S^T[key=t*16+quad*4+r][q=lo]
        floatx4 s[2][4];
        #pragma unroll
        for (int t = 0; t < 4; ++t) {
            const int rw = (t * 16 + lo) * 64;
            const short8 kf0 = *(const short8*)(Ks + rw + pos0);
            const short8 kf1 = *(const short8*)(Ks + rw + pos1);
            #pragma unroll
            for (int qt = 0; qt < 2; ++qt) {
                s[qt][t] = __builtin_amdgcn_mfma_f32_16x16x32_bf16(
                    kf0, qf[qt][0], (floatx4){0.f, 0.f, 0.f, 0.f}, 0, 0, 0);
                s[qt][t] = __builtin_amdgcn_mfma_f32_16x16x32_bf16(
                    kf1, qf[qt][1], s[qt][t], 0, 0, 0);
            }
        }

        // P = exp2(s); truncating bf16 pack (bias cancels in O/l ratio)
        #pragma unroll
        for (int qt = 0; qt < 2; ++qt)
            #pragma unroll
            for (int t = 0; t < 4; ++t) {
                unsigned u0 = __builtin_bit_cast(unsigned, __builtin_amdgcn_exp2f(s[qt][t][0]));
                unsigned u1 = __builtin_bit_cast(unsigned, __builtin_amdgcn_exp2f(s[qt][t][1]));
                unsigned u2 = __builtin_bit_cast(unsigned, __builtin_amdgcn_exp2f(s[qt][t][2]));
                unsigned u3 = __builtin_bit_cast(unsigned, __builtin_amdgcn_exp2f(s[qt][t][3]));
                uint2 pk = {(u0 >> 16) | (u1 & 0xFFFF0000u),
                            (u2 >> 16) | (u3 & 0xFFFF0000u)};
                *(uint2*)(pw + (qt * 16 + lo) * PRS + t * 16 + quad * 4) = pk;
            }

        short8 pf[2][2];
        #pragma unroll
        for (int qt = 0; qt < 2; ++qt) {
            pf[qt][0] = *(const short8*)(pw + (qt * 16 + lo) * PRS + quad * 8);
            pf[qt][1] = *(const short8*)(pw + (qt * 16 + lo) * PRS + 32 + quad * 8);
            lacc[qt] = __builtin_amdgcn_mfma_f32_16x16x32_bf16(pf[qt][0], ones, lacc[qt], 0, 0, 0);
            lacc[qt] = __builtin_amdgcn_mfma_f32_16x16x32_bf16(pf[qt][1], ones, lacc[qt], 0, 0, 0);
        }

        #pragma unroll
        for (int cb = 0; cb < 4; ++cb) {
            const int rw = (cb * 16 + lo) * 64;
            const short8 vf0 = *(const short8*)(Vs + rw + pos0);
            const short8 vf1 = *(const short8*)(Vs + rw + pos1);
            #pragma unroll
            for (int qt = 0; qt < 2; ++qt) {
                acc[qt][cb] = __builtin_amdgcn_mfma_f32_16x16x32_bf16(pf[qt][0], vf0, acc[qt][cb], 0, 0, 0);
                acc[qt][cb] = __builtin_amdgcn_mfma_f32_16x16x32_bf16(pf[qt][1], vf1, acc[qt][cb], 0, 0, 0);
            }
        }
        __syncthreads();
    }

    float* ca = ksp ? cacc1 : cacc0;
    float* lb = lbuf + (size_t)ksp * (NB * NH * NS);
    #pragma unroll
    for (int qt = 0; qt < 2; ++qt) {
        #pragma unroll
        for (int cb = 0; cb < 4; ++cb)
            #pragma unroll
            for (int r = 0; r < 4; ++r) {
                size_t off = (size_t)(b * NS + q0 + qt * 16 + quad * 4 + r) * ND
                           + h * NDK + cb * 16 + lo;
                ca[off] = acc[qt][cb][r];
            }
        if (lo == 0)
            #pragma unroll
            for (int r = 0; r < 4; ++r)
                lb[(size_t)bh * NS + q0 + qt * 16 + quad * 4 + r] = lacc[qt][r];
    }
}

// ---------------------------------------------------------------------------
// Output projection with fused softmax-divide:
//   ctx[row][col] = (cacc0+cacc1)*rcp(l0+l1)  (packed to bf16 in staging)
//   out = ctx @ Wo^T + bo   (fp32 out). BM=64 BN=128 BK=64, 512 blocks.
// All A-chunk cols in one BK step share head h = k0/64 -> one l per row/iter.
// ---------------------------------------------------------------------------
__global__ __launch_bounds__(256) void gemm_o(
    const float* __restrict__ cacc0, const float* __restrict__ cacc1,
    const float* __restrict__ lbuf, const float* __restrict__ Bw,
    const float* __restrict__ bias, float* __restrict__ Cout)
{
    __shared__ unsigned short As[64 * 64];
    __shared__ unsigned short Bs[128 * 64];
    const int tid = threadIdx.x, w = tid >> 6, lane = tid & 63;
    const int lo = lane & 15, quad = lane >> 4;
    const int bn = blockIdx.x, bm = blockIdx.y;
    const int K = ND;
    const int wm = (w >> 1) * 32, wn = (w & 1) * 64;
    const size_t LHALF = (size_t)NB * NH * NS;

    // A chunks: c0=tid (row tid>>3), c1=tid+256 (row+32); same g for both
    const int ar = tid >> 3;
    const int ag = (tid & 7) ^ (ar & 7);
    const int tok0 = bm * 64 + ar, tok1 = tok0 + 32;
    const float* A00 = cacc0 + (size_t)tok0 * ND + ag * 8;
    const float* A01 = cacc1 + (size_t)tok0 * ND + ag * 8;
    const float* A10 = cacc0 + (size_t)tok1 * ND + ag * 8;
    const float* A11 = cacc1 + (size_t)tok1 * ND + ag * 8;
    // l index base: ((b<<4)+h)*NS + sq, h added per-iter
    const size_t lb0 = (size_t)((tok0 >> 11) << 4) * NS + (tok0 & (NS - 1));
    const size_t lb1 = (size_t)((tok1 >> 11) << 4) * NS + (tok1 & (NS - 1));
    unsigned short* AsD0 = As + tid * 8;
    unsigned short* AsD1 = As + (tid + 256) * 8;

    const float* Bg[4];
    unsigned short* BsD[4];
    #pragma unroll
    for (int p = 0; p < 4; ++p) {
        int c = tid + 256 * p, r = c >> 3, g = (c & 7) ^ (r & 7);
        Bg[p] = Bw + (size_t)(bn * 128 + r) * K + g * 8;
        BsD[p] = Bs + c * 8;
    }

    floatx4 acc[2][4];
    #pragma unroll
    for (int i = 0; i < 2; ++i)
        #pragma unroll
        for (int j = 0; j < 4; ++j) acc[i][j] = (floatx4){0.f, 0.f, 0.f, 0.f};

    // prefetch first tile + l values
    float4 ra[8], rb[8];
    float lv0, lv1;
    {
        ra[0] = *(const float4*)(A00);     ra[1] = *(const float4*)(A00 + 4);
        ra[2] = *(const float4*)(A01);     ra[3] = *(const float4*)(A01 + 4);
        ra[4] = *(const float4*)(A10);     ra[5] = *(const float4*)(A10 + 4);
        ra[6] = *(const float4*)(A11);     ra[7] = *(const float4*)(A11 + 4);
        #pragma unroll
        for (int p = 0; p < 4; ++p) {
            rb[2 * p]     = *(const float4*)(Bg[p]);
            rb[2 * p + 1] = *(const float4*)(Bg[p] + 4);
        }
        lv0 = lbuf[lb0] + lbuf[lb0 + LHALF];
        lv1 = lbuf[lb1] + lbuf[lb1 + LHALF];
    }

    for (int k0 = 0; k0 < K; k0 += 64) {
        const float inv0 = __builtin_amdgcn_rcpf(lv0);
        const float inv1 = __builtin_amdgcn_rcpf(lv1);
        __syncthreads();
        {
            float4 s0 = {(ra[0].x + ra[2].x) * inv0, (ra[0].y + ra[2].y) * inv0,
                         (ra[0].z + ra[2].z) * inv0, (ra[0].w + ra[2].w) * inv0};
            float4 s1 = {(ra[1].x + ra[3].x) * inv0, (ra[1].y + ra[3].y) * inv0,
                         (ra[1].z + ra[3].z) * inv0, (ra[1].w + ra[3].w) * inv0};
            *(uint4*)AsD0 = pack8(s0, s1);
            float4 s2 = {(ra[4].x + ra[6].x) * inv1, (ra[4].y + ra[6].y) * inv1,
                         (ra[4].z + ra[6].z) * inv1, (ra[4].w + ra[6].w) * inv1};
            float4 s3 = {(ra[5].x + ra[7].x) * inv1, (ra[5].y + ra[7].y) * inv1,
                         (ra[5].z + ra[7].z) * inv1, (ra[5].w + ra[7].w) * inv1};
            *(uint4*)AsD1 = pack8(s2, s3);
        }
        #pragma unroll
        for (int p = 0; p < 4; ++p)
            *(uint4*)BsD[p] = pack8(rb[2 * p], rb[2 * p + 1]);
        __syncthreads();

        const int kn = k0 + 64;
        if (kn < K) {
            ra[0] = *(const float4*)(A00 + kn); ra[1] = *(const float4*)(A00 + kn + 4);
            ra[2] = *(const float4*)(A01 + kn); ra[3] = *(const float4*)(A01 + kn + 4);
            ra[4] = *(const float4*)(A10 + kn); ra[5] = *(const float4*)(A10 + kn + 4);
            ra[6] = *(const float4*)(A11 + kn); ra[7] = *(const float4*)(A11 + kn + 4);
            #pragma unroll
            for (int p = 0; p < 4; ++p) {
                rb[2 * p]     = *(const float4*)(Bg[p] + kn);
                rb[2 * p + 1] = *(const float4*)(Bg[p] + kn + 4);
            }
            const size_t hoff = (size_t)(kn >> 6) * NS;
            lv0 = lbuf[lb0 + hoff] + lbuf[lb0 + hoff + LHALF];
            lv1 = lbuf[lb1 + hoff] + lbuf[lb1 + hoff + LHALF];
        }

        #pragma unroll
        for (int s = 0; s < 2; ++s) {
            const int pos = ((s * 4 + quad) ^ (lo & 7)) * 8;
            short8 af[2], bf[4];
            #pragma unroll
            for (int i = 0; i < 2; ++i)
                af[i] = *(const short8*)(As + (wm + i * 16 + lo) * 64 + pos);
            #pragma unroll
            for (int j = 0; j < 4; ++j)
                bf[j] = *(const short8*)(Bs + (wn + j * 16 + lo) * 64 + pos);
            #pragma unroll
            for (int i = 0; i < 2; ++i)
                #pragma unroll
                for (int j = 0; j < 4; ++j)
                    acc[i][j] = __builtin_amdgcn_mfma_f32_16x16x32_bf16(af[i], bf[j], acc[i][j], 0, 0, 0);
        }
    }

    #pragma unroll
    for (int j = 0; j < 4; ++j) {
        const int col = bn * 128 + wn + j * 16 + lo;
        const float bb = bias[col];
        #pragma unroll
        for (int i = 0; i < 2; ++i)
            #pragma unroll
            for (int r = 0; r < 4; ++r) {
                const int row = bm * 64 + wm + i * 16 + quad * 4 + r;
                Cout[(size_t)row * ND + col] = acc[i][j][r] + bb;
            }
    }
}

// ---------------------------------------------------------------------------
extern "C" void kernel_launch(void* const* d_in, const int* in_sizes, int n_in,
                              void* d_out, int out_size, void* d_ws, size_t ws_size,
                              hipStream_t stream)
{
    const float* query = (const float*)d_in[0];
    const float* key   = (const float*)d_in[1];
    const float* value = (const float*)d_in[2];
    const float* Wq    = (const float*)d_in[3];
    const float* bq    = (const float*)d_in[4];
    const float* Wk    = (const float*)d_in[5];
    const float* bk    = (const float*)d_in[6];
    const float* Wv    = (const float*)d_in[7];
    const float* bv    = (const float*)d_in[8];
    const float* Wo    = (const float*)d_in[9];
    const float* bo    = (const float*)d_in[10];
    float* out = (float*)d_out;

    const size_t n = (size_t)NB * NS * ND;   // 4,194,304

    unsigned short* qbuf = (unsigned short*)d_ws;
    unsigned short* kbuf = qbuf + n;
    unsigned short* vtb  = kbuf + n;
    float* cacc0 = (float*)(vtb + n);
    float* cacc1 = cacc0 + n;
    float* lbuf  = cacc1 + n;                // 2 x NB*NH*NS f32

    const int M = NB * NS;  // 4096

    gemm_qkv<<<768, 256, 0, stream>>>(query, key, value, Wq, Wk, Wv,
                                      bq, bk, bv, qbuf, kbuf, vtb);

    attn_mfma<<<dim3(NS / 128, 2, NB * NH), 256, 0, stream>>>(
        qbuf, kbuf, vtb, cacc0, cacc1, lbuf);

    gemm_o<<<dim3(ND / 128, M / 64), 256, 0, stream>>>(
        cacc0, cacc1, lbuf, Wo, bo, out);
}

// Round 9
// 233.062 us; speedup vs baseline: 1.1548x; 1.1548x over previous
//
#include <hip/hip_runtime.h>
#include <math.h>

constexpr int NB = 2;
constexpr int NS = 2048;
constexpr int ND = 1024;
constexpr int NH = 16;
constexpr int NDK = 64;

typedef __attribute__((ext_vector_type(8))) short short8;
typedef __attribute__((ext_vector_type(4))) float floatx4;

__device__ inline unsigned short f2bf(float x) {
    unsigned u = __builtin_bit_cast(unsigned, x);
    u += 0x7fffu + ((u >> 16) & 1u);          // RNE
    return (unsigned short)(u >> 16);
}

__device__ inline uint4 pack8(float4 a, float4 b) {
    unsigned short t[8] = {f2bf(a.x), f2bf(a.y), f2bf(a.z), f2bf(a.w),
                           f2bf(b.x), f2bf(b.y), f2bf(b.z), f2bf(b.w)};
    return *(uint4*)t;
}

#define GLOAD_LDS16(g, l) __builtin_amdgcn_global_load_lds( \
    (const __attribute__((address_space(1))) void*)(g),     \
    (__attribute__((address_space(3))) void*)(l), 16, 0, 0)

// scale folded into Q projection: exp(s/8) == exp2(s * 0.125 * log2(e))
#define QSCALE 0.18033688f

// ---------------------------------------------------------------------------
// single fused fp32 -> bf16 convert for all 7 tensors (blockIdx.y selects)
// ---------------------------------------------------------------------------
__global__ __launch_bounds__(256) void cvt_all(
    const float* __restrict__ s0, const float* __restrict__ s1,
    const float* __restrict__ s2, const float* __restrict__ s3,
    const float* __restrict__ s4, const float* __restrict__ s5,
    const float* __restrict__ s6,
    unsigned short* __restrict__ d0, unsigned short* __restrict__ d1,
    unsigned short* __restrict__ d2, unsigned short* __restrict__ d3,
    unsigned short* __restrict__ d4, unsigned short* __restrict__ d5,
    unsigned short* __restrict__ d6)
{
    const int y = blockIdx.y;
    const float* srcs[7] = {s0, s1, s2, s3, s4, s5, s6};
    unsigned short* dsts[7] = {d0, d1, d2, d3, d4, d5, d6};
    const int nel = (y < 3) ? NB * NS * ND : ND * ND;
    int i = (blockIdx.x * 256 + threadIdx.x) * 8;
    if (i >= nel) return;
    const float* s = srcs[y];
    unsigned short* d = dsts[y];
    float4 a = *(const float4*)(s + i);
    float4 b = *(const float4*)(s + i + 4);
    *(uint4*)(d + i) = pack8(a, b);
}

// ---------------------------------------------------------------------------
// Fused QKV projection, 128x128 tile, BK=32, bf16 in, global_load_lds staging.
// XCD swizzle: the 8 (seg0/1) / 8 (seg2) blocks sharing an A/B data tile get
// equal bid%8 -> same XCD -> tile fetched once per XCD instead of 8x.
//   seg 0: qbuf = (Xq @ Wq^T + bq) * QSCALE      (bf16)
//   seg 1: kbuf =  Xk @ Wk^T + bk                (bf16)
//   seg 2: vt[(b*ND+d)][s] = Wv @ Xv^T + bv      (V^T direct, bf16)
// ---------------------------------------------------------------------------
__global__ __launch_bounds__(256) void gemm_qkv(
    const unsigned short* __restrict__ Xq, const unsigned short* __restrict__ Xk,
    const unsigned short* __restrict__ Xv,
    const unsigned short* __restrict__ Wq, const unsigned short* __restrict__ Wk,
    const unsigned short* __restrict__ Wv,
    const float* __restrict__ bq, const float* __restrict__ bk,
    const float* __restrict__ bv,
    unsigned short* __restrict__ Cq, unsigned short* __restrict__ Ck,
    unsigned short* __restrict__ Cv)
{
    __shared__ unsigned short As[128 * 32];
    __shared__ unsigned short Bs[128 * 32];
    const int tid = threadIdx.x, w = tid >> 6, lane = tid & 63;
    const int lo = lane & 15, quad = lane >> 4;
    const int bid = blockIdx.x;
    const int seg = bid >> 8;          // 0,1,2 (256 blocks each)
    const int wi  = bid & 255;
    const int xcd = wi & 7;
    const int t   = wi >> 3;           // 0..31
    const int K = ND;

    int bm, bn;
    const unsigned short *A, *Bw;
    const float* bias;
    if (seg == 2) {
        // A=Wv (8 bm tiles), B=Xv tokens (32 bn tiles). Same-bn group on one XCD.
        bm = t & 7; bn = (t >> 3) * 8 + xcd;
        A = Wv; Bw = Xv; bias = bv;
    } else {
        // A=X tokens (32 bm), B=W (8 bn). Same-bm group on one XCD.
        bn = t & 7; bm = (t >> 3) * 8 + xcd;
        if (seg == 1) { A = Xk; Bw = Wk; bias = bk; }
        else          { A = Xq; Bw = Wq; bias = bq; }
    }

    const int wm = (w >> 1) * 64, wn = (w & 1) * 64;

    // staging: 128 rows x 32 elems = 4 x 16B chunks/row, 2 chunks/thread.
    // LDS position p of row r holds global chunk p ^ (r&3).
    const int srow = tid >> 2;
    const int sch = (tid & 3) ^ (srow & 3);
    const unsigned short* Ag0 = A + (size_t)(bm * 128 + srow) * K + sch * 8;
    const unsigned short* Ag1 = Ag0 + (size_t)64 * K;
    const unsigned short* Bg0 = Bw + (size_t)(bn * 128 + srow) * K + sch * 8;
    const unsigned short* Bg1 = Bg0 + (size_t)64 * K;
    unsigned short* AsD0 = As + tid * 8;
    unsigned short* AsD1 = As + (tid + 256) * 8;
    unsigned short* BsD0 = Bs + tid * 8;
    unsigned short* BsD1 = Bs + (tid + 256) * 8;

    floatx4 acc[4][4];
    #pragma unroll
    for (int i = 0; i < 4; ++i)
        #pragma unroll
        for (int j = 0; j < 4; ++j) acc[i][j] = (floatx4){0.f, 0.f, 0.f, 0.f};

    const int rpos = (quad ^ (lo & 3)) * 8;

    for (int k0 = 0; k0 < K; k0 += 32) {
        GLOAD_LDS16(Ag0 + k0, AsD0);
        GLOAD_LDS16(Ag1 + k0, AsD1);
        GLOAD_LDS16(Bg0 + k0, BsD0);
        GLOAD_LDS16(Bg1 + k0, BsD1);
        __syncthreads();

        short8 af[4], bf[4];
        #pragma unroll
        for (int i = 0; i < 4; ++i)
            af[i] = *(const short8*)(As + (wm + i * 16 + lo) * 32 + rpos);
        #pragma unroll
        for (int j = 0; j < 4; ++j)
            bf[j] = *(const short8*)(Bs + (wn + j * 16 + lo) * 32 + rpos);

        #pragma unroll
        for (int i = 0; i < 4; ++i)
            #pragma unroll
            for (int j = 0; j < 4; ++j)
                acc[i][j] = __builtin_amdgcn_mfma_f32_16x16x32_bf16(af[i], bf[j], acc[i][j], 0, 0, 0);
        __syncthreads();
    }

    if (seg < 2) {
        unsigned short* C = seg ? Ck : Cq;
        const float scale = seg ? 1.f : QSCALE;
        #pragma unroll
        for (int j = 0; j < 4; ++j) {
            const int col = bn * 128 + wn + j * 16 + lo;
            const float bb = bias[col];
            #pragma unroll
            for (int i = 0; i < 4; ++i)
                #pragma unroll
                for (int r = 0; r < 4; ++r) {
                    const int row = bm * 128 + wm + i * 16 + quad * 4 + r;
                    C[(size_t)row * ND + col] = f2bf((acc[i][j][r] + bb) * scale);
                }
        }
    } else {
        // rows = d (0..1023), cols = tokens; write vt[(b*ND + d)*NS + s]
        #pragma unroll
        for (int i = 0; i < 4; ++i)
            #pragma unroll
            for (int r = 0; r < 4; ++r) {
                const int row = bm * 128 + wm + i * 16 + quad * 4 + r;
                const float bb = bias[row];
                #pragma unroll
                for (int j = 0; j < 4; ++j) {
                    const int col = bn * 128 + wn + j * 16 + lo;
                    const int b = col >> 11, s = col & (NS - 1);
                    Cv[(size_t)(b * ND + row) * NS + s] = f2bf(acc[i][j][r] + bb);
                }
            }
    }
}

// ---------------------------------------------------------------------------
// MFMA flash attention, K-split x2 into separate partial buffers.
// XCD swizzle: the 16 q-group blocks sharing one (bh,ksp) K/V half get equal
// bid%8 -> same XCD.
// ---------------------------------------------------------------------------
constexpr int PRS = 72;

__global__ __launch_bounds__(256, 4) void attn_mfma(
    const unsigned short* __restrict__ qb,
    const unsigned short* __restrict__ kb,
    const unsigned short* __restrict__ vt,
    float* __restrict__ cacc0, float* __restrict__ cacc1,
    float* __restrict__ lbuf)
{
    __shared__ unsigned short Ks[64 * 64];
    __shared__ unsigned short Vs[64 * 64];
    __shared__ unsigned short Pt[4][32 * PRS];

    const int tid = threadIdx.x, w = tid >> 6, lane = tid & 63;
    const int lo = lane & 15, quad = lane >> 4;
    const int bid = blockIdx.x;                 // 0..1023
    const int xcd = bid & 7;
    const int tt  = bid >> 3;                   // 0..127
    const int qgrp = tt & 15;
    const int bhk  = (tt >> 4) * 8 + xcd;       // 0..63, same for 16 qgrps
    const int bh = bhk >> 1, ksp = bhk & 1;
    const int b = bh >> 4, h = bh & 15;
    const int q0 = qgrp * 128 + w * 32;

    short8 qf[2][2];
    #pragma unroll
    for (int qt = 0; qt < 2; ++qt) {
        const unsigned short* qrow =
            qb + (size_t)(b * NS + q0 + qt * 16 + lo) * ND + h * NDK + quad * 8;
        qf[qt][0] = *(const short8*)(qrow);
        qf[qt][1] = *(const short8*)(qrow + 32);
    }

    // staging: 64-row x 128B tiles = 512 x 16B chunks, 2 per thread
    const int c0 = tid, c1 = tid + 256;
    const int r0 = c0 >> 3, g0 = (c0 & 7) ^ (r0 & 7);
    const int r1 = c1 >> 3, g1 = (c1 & 7) ^ (r1 & 7);
    const unsigned short* Ksrc0 = kb + (size_t)(b * NS + r0) * ND + h * NDK + g0 * 8;
    const unsigned short* Ksrc1 = kb + (size_t)(b * NS + r1) * ND + h * NDK + g1 * 8;
    const unsigned short* Vsrc0 = vt + (size_t)(bh * NDK + r0) * NS + g0 * 8;
    const unsigned short* Vsrc1 = vt + (size_t)(bh * NDK + r1) * NS + g1 * 8;
    unsigned short* Kd0 = Ks + c0 * 8;
    unsigned short* Kd1 = Ks + c1 * 8;
    unsigned short* Vd0 = Vs + c0 * 8;
    unsigned short* Vd1 = Vs + c1 * 8;

    floatx4 acc[2][4], lacc[2];
    #pragma unroll
    for (int qt = 0; qt < 2; ++qt) {
        lacc[qt] = (floatx4){0.f, 0.f, 0.f, 0.f};
        #pragma unroll
        for (int cb = 0; cb < 4; ++cb) acc[qt][cb] = (floatx4){0.f, 0.f, 0.f, 0.f};
    }

    const short8 ones = {0x3F80, 0x3F80, 0x3F80, 0x3F80,
                         0x3F80, 0x3F80, 0x3F80, 0x3F80};
    unsigned short* pw = &Pt[w][0];
    const int pos0 = (quad ^ (lo & 7)) * 8;
    const int pos1 = ((4 + quad) ^ (lo & 7)) * 8;

    for (int key0 = ksp * 1024; key0 < ksp * 1024 + 1024; key0 += 64) {
        GLOAD_LDS16(Ksrc0 + (size_t)key0 * ND, Kd0);
        GLOAD_LDS16(Ksrc1 + (size_t)key0 * ND, Kd1);
        GLOAD_LDS16(Vsrc0 + key0, Vd0);
        GLOAD_LDS16(Vsrc1 + key0, Vd1);
        __syncthreads();

        // S^T = K @ Q^T : lane holds S^T[key=t*16+quad*4+r][q=lo]
        floatx4 s[2][4];
        #pragma unroll
        for (int t = 0; t < 4; ++t) {
            const int rw = (t * 16 + lo) * 64;
            const short8 kf0 = *(const short8*)(Ks + rw + pos0);
            const short8 kf1 = *(const short8*)(Ks + rw + pos1);
            #pragma unroll
            for (int qt = 0; qt < 2; ++qt) {
                s[qt][t] = __builtin_amdgcn_mfma_f32_16x16x32_bf16(
                    kf0, qf[qt][0], (floatx4){0.f, 0.f, 0.f, 0.f}, 0, 0, 0);
                s[qt][t] = __builtin_amdgcn_mfma_f32_16x16x32_bf16(
                    kf1, qf[qt][1], s[qt][t], 0, 0, 0);
            }
        }

        // P = exp2(s); truncating bf16 pack (bias cancels in O/l ratio)
        #pragma unroll
        for (int qt = 0; qt < 2; ++qt)
            #pragma unroll
            for (int t = 0; t < 4; ++t) {
                unsigned u0 = __builtin_bit_cast(unsigned, __builtin_amdgcn_exp2f(s[qt][t][0]));
                unsigned u1 = __builtin_bit_cast(unsigned, __builtin_amdgcn_exp2f(s[qt][t][1]));
                unsigned u2 = __builtin_bit_cast(unsigned, __builtin_amdgcn_exp2f(s[qt][t][2]));
                unsigned u3 = __builtin_bit_cast(unsigned, __builtin_amdgcn_exp2f(s[qt][t][3]));
                uint2 pk = {(u0 >> 16) | (u1 & 0xFFFF0000u),
                            (u2 >> 16) | (u3 & 0xFFFF0000u)};
                *(uint2*)(pw + (qt * 16 + lo) * PRS + t * 16 + quad * 4) = pk;
            }

        short8 pf[2][2];
        #pragma unroll
        for (int qt = 0; qt < 2; ++qt) {
            pf[qt][0] = *(const short8*)(pw + (qt * 16 + lo) * PRS + quad * 8);
            pf[qt][1] = *(const short8*)(pw + (qt * 16 + lo) * PRS + 32 + quad * 8);
            lacc[qt] = __builtin_amdgcn_mfma_f32_16x16x32_bf16(pf[qt][0], ones, lacc[qt], 0, 0, 0);
            lacc[qt] = __builtin_amdgcn_mfma_f32_16x16x32_bf16(pf[qt][1], ones, lacc[qt], 0, 0, 0);
        }

        #pragma unroll
        for (int cb = 0; cb < 4; ++cb) {
            const int rw = (cb * 16 + lo) * 64;
            const short8 vf0 = *(const short8*)(Vs + rw + pos0);
            const short8 vf1 = *(const short8*)(Vs + rw + pos1);
            #pragma unroll
            for (int qt = 0; qt < 2; ++qt) {
                acc[qt][cb] = __builtin_amdgcn_mfma_f32_16x16x32_bf16(pf[qt][0], vf0, acc[qt][cb], 0, 0, 0);
                acc[qt][cb] = __builtin_amdgcn_mfma_f32_16x16x32_bf16(pf[qt][1], vf1, acc[qt][cb], 0, 0, 0);
            }
        }
        __syncthreads();
    }

    float* ca = ksp ? cacc1 : cacc0;
    float* lb = lbuf + (size_t)ksp * (NB * NH * NS);
    #pragma unroll
    for (int qt = 0; qt < 2; ++qt) {
        #pragma unroll
        for (int cb = 0; cb < 4; ++cb)
            #pragma unroll
            for (int r = 0; r < 4; ++r) {
                size_t off = (size_t)(b * NS + q0 + qt * 16 + quad * 4 + r) * ND
                           + h * NDK + cb * 16 + lo;
                ca[off] = acc[qt][cb][r];
            }
        if (lo == 0)
            #pragma unroll
            for (int r = 0; r < 4; ++r)
                lb[(size_t)bh * NS + q0 + qt * 16 + quad * 4 + r] = lacc[qt][r];
    }
}

// ---------------------------------------------------------------------------
// Output projection with fused softmax-divide.
//   A-path: ctx = (cacc0+cacc1)*rcp(l0+l1), fp32 loads -> bf16 pack -> LDS
//           (one head per BK=64 step -> one l per row per iter)
//   B-path: bf16 Wo via global_load_lds.
// BM=64 BN=128 BK=64, 512 blocks, XCD swizzle on A-sharing groups.
// ---------------------------------------------------------------------------
__global__ __launch_bounds__(256) void gemm_o(
    const float* __restrict__ cacc0, const float* __restrict__ cacc1,
    const float* __restrict__ lbuf, const unsigned short* __restrict__ Bw,
    const float* __restrict__ bias, float* __restrict__ Cout)
{
    __shared__ unsigned short As[64 * 64];
    __shared__ unsigned short Bs[128 * 64];
    const int tid = threadIdx.x, w = tid >> 6, lane = tid & 63;
    const int lo = lane & 15, quad = lane >> 4;
    const int bid = blockIdx.x;                // 0..511
    const int xcd = bid & 7;
    const int tt  = bid >> 3;                  // 0..63
    const int bn  = tt & 7;
    const int bm  = (tt >> 3) * 8 + xcd;       // 8 bn-blocks of same bm share XCD
    const int K = ND;
    const int wm = (w >> 1) * 32, wn = (w & 1) * 64;
    const size_t LHALF = (size_t)NB * NH * NS;

    // A chunks: c0=tid (row tid>>3), c1=tid+256 (row+32); same g for both
    const int ar = tid >> 3;
    const int ag = (tid & 7) ^ (ar & 7);
    const int tok0 = bm * 64 + ar, tok1 = tok0 + 32;
    const float* A00 = cacc0 + (size_t)tok0 * ND + ag * 8;
    const float* A01 = cacc1 + (size_t)tok0 * ND + ag * 8;
    const float* A10 = cacc0 + (size_t)tok1 * ND + ag * 8;
    const float* A11 = cacc1 + (size_t)tok1 * ND + ag * 8;
    const size_t lb0 = (size_t)((tok0 >> 11) << 4) * NS + (tok0 & (NS - 1));
    const size_t lb1 = (size_t)((tok1 >> 11) << 4) * NS + (tok1 & (NS - 1));
    unsigned short* AsD0 = As + tid * 8;
    unsigned short* AsD1 = As + (tid + 256) * 8;

    const unsigned short* Bg[4];
    unsigned short* BsD[4];
    #pragma unroll
    for (int p = 0; p < 4; ++p) {
        int c = tid + 256 * p, r = c >> 3, g = (c & 7) ^ (r & 7);
        Bg[p] = Bw + (size_t)(bn * 128 + r) * K + g * 8;
        BsD[p] = Bs + c * 8;
    }

    floatx4 acc[2][4];
    #pragma unroll
    for (int i = 0; i < 2; ++i)
        #pragma unroll
        for (int j = 0; j < 4; ++j) acc[i][j] = (floatx4){0.f, 0.f, 0.f, 0.f};

    // prefetch first A tile + l values
    float4 ra[8];
    float lv0, lv1;
    ra[0] = *(const float4*)(A00);     ra[1] = *(const float4*)(A00 + 4);
    ra[2] = *(const float4*)(A01);     ra[3] = *(const float4*)(A01 + 4);
    ra[4] = *(const float4*)(A10);     ra[5] = *(const float4*)(A10 + 4);
    ra[6] = *(const float4*)(A11);     ra[7] = *(const float4*)(A11 + 4);
    lv0 = lbuf[lb0] + lbuf[lb0 + LHALF];
    lv1 = lbuf[lb1] + lbuf[lb1 + LHALF];

    for (int k0 = 0; k0 < K; k0 += 64) {
        const float inv0 = __builtin_amdgcn_rcpf(lv0);
        const float inv1 = __builtin_amdgcn_rcpf(lv1);
        __syncthreads();
        #pragma unroll
        for (int p = 0; p < 4; ++p) GLOAD_LDS16(Bg[p] + k0, BsD[p]);
        {
            float4 s0 = {(ra[0].x + ra[2].x) * inv0, (ra[0].y + ra[2].y) * inv0,
                         (ra[0].z + ra[2].z) * inv0, (ra[0].w + ra[2].w) * inv0};
            float4 s1 = {(ra[1].x + ra[3].x) * inv0, (ra[1].y + ra[3].y) * inv0,
                         (ra[1].z + ra[3].z) * inv0, (ra[1].w + ra[3].w) * inv0};
            *(uint4*)AsD0 = pack8(s0, s1);
            float4 s2 = {(ra[4].x + ra[6].x) * inv1, (ra[4].y + ra[6].y) * inv1,
                         (ra[4].z + ra[6].z) * inv1, (ra[4].w + ra[6].w) * inv1};
            float4 s3 = {(ra[5].x + ra[7].x) * inv1, (ra[5].y + ra[7].y) * inv1,
                         (ra[5].z + ra[7].z) * inv1, (ra[5].w + ra[7].w) * inv1};
            *(uint4*)AsD1 = pack8(s2, s3);
        }
        __syncthreads();

        const int kn = k0 + 64;
        if (kn < K) {
            ra[0] = *(const float4*)(A00 + kn); ra[1] = *(const float4*)(A00 + kn + 4);
            ra[2] = *(const float4*)(A01 + kn); ra[3] = *(const float4*)(A01 + kn + 4);
            ra[4] = *(const float4*)(A10 + kn); ra[5] = *(const float4*)(A10 + kn + 4);
            ra[6] = *(const float4*)(A11 + kn); ra[7] = *(const float4*)(A11 + kn + 4);
            const size_t hoff = (size_t)(kn >> 6) * NS;
            lv0 = lbuf[lb0 + hoff] + lbuf[lb0 + hoff + LHALF];
            lv1 = lbuf[lb1 + hoff] + lbuf[lb1 + hoff + LHALF];
        }

        #pragma unroll
        for (int s = 0; s < 2; ++s) {
            const int pos = ((s * 4 + quad) ^ (lo & 7)) * 8;
            short8 af[2], bf[4];
            #pragma unroll
            for (int i = 0; i < 2; ++i)
                af[i] = *(const short8*)(As + (wm + i * 16 + lo) * 64 + pos);
            #pragma unroll
            for (int j = 0; j < 4; ++j)
                bf[j] = *(const short8*)(Bs + (wn + j * 16 + lo) * 64 + pos);
            #pragma unroll
            for (int i = 0; i < 2; ++i)
                #pragma unroll
                for (int j = 0; j < 4; ++j)
                    acc[i][j] = __builtin_amdgcn_mfma_f32_16x16x32_bf16(af[i], bf[j], acc[i][j], 0, 0, 0);
        }
    }

    #pragma unroll
    for (int j = 0; j < 4; ++j) {
        const int col = bn * 128 + wn + j * 16 + lo;
        const float bb = bias[col];
        #pragma unroll
        for (int i = 0; i < 2; ++i)
            #pragma unroll
            for (int r = 0; r < 4; ++r) {
                const int row = bm * 64 + wm + i * 16 + quad * 4 + r;
                Cout[(size_t)row * ND + col] = acc[i][j][r] + bb;
            }
    }
}

// ---------------------------------------------------------------------------
extern "C" void kernel_launch(void* const* d_in, const int* in_sizes, int n_in,
                              void* d_out, int out_size, void* d_ws, size_t ws_size,
                              hipStream_t stream)
{
    const float* query = (const float*)d_in[0];
    const float* key   = (const float*)d_in[1];
    const float* value = (const float*)d_in[2];
    const float* Wq    = (const float*)d_in[3];
    const float* bq    = (const float*)d_in[4];
    const float* Wk    = (const float*)d_in[5];
    const float* bk    = (const float*)d_in[6];
    const float* Wv    = (const float*)d_in[7];
    const float* bv    = (const float*)d_in[8];
    const float* Wo    = (const float*)d_in[9];
    const float* bo    = (const float*)d_in[10];
    float* out = (float*)d_out;

    const size_t n  = (size_t)NB * NS * ND;   // 4,194,304
    const size_t nw = (size_t)ND * ND;        // 1,048,576

    unsigned short* X0   = (unsigned short*)d_ws;  // query bf16
    unsigned short* X1   = X0 + n;                 // key bf16   -> cacc0 (w/ X2)
    unsigned short* X2   = X1 + n;                 // value bf16
    unsigned short* W0   = X2 + n;
    unsigned short* W1   = W0 + nw;
    unsigned short* W2   = W1 + nw;
    unsigned short* W3   = W2 + nw;
    unsigned short* qbuf = W3 + nw;
    unsigned short* kbuf = qbuf + n;
    unsigned short* vtb  = kbuf + n;
    float* cacc1 = (float*)(vtb + n);              // n f32
    float* lbuf  = cacc1 + n;                      // 2 x NB*NH*NS f32
    float* cacc0 = (float*)X1;                     // n f32, overlays X1+X2

    const int M = NB * NS;  // 4096

    cvt_all<<<dim3((int)(n / 2048), 7), 256, 0, stream>>>(
        query, key, value, Wq, Wk, Wv, Wo, X0, X1, X2, W0, W1, W2, W3);

    gemm_qkv<<<768, 256, 0, stream>>>(X0, X1, X2, W0, W1, W2,
                                      bq, bk, bv, qbuf, kbuf, vtb);

    attn_mfma<<<1024, 256, 0, stream>>>(qbuf, kbuf, vtb, cacc0, cacc1, lbuf);

    gemm_o<<<512, 256, 0, stream>>>(cacc0, cacc1, lbuf, W3, bo, out);
}